// Round 1
// baseline (7467.473 us; speedup 1.0000x reference)
//
#include <hip/hip_runtime.h>

#define BB 256
#define TT 512
#define DD 256
#define UU 512

typedef float f32x4 __attribute__((ext_vector_type(4)));
typedef __bf16 bf16x8 __attribute__((ext_vector_type(8)));

#define GLOAD_LDS16(gp, lp)                                                              \
  __builtin_amdgcn_global_load_lds((const __attribute__((address_space(1))) void*)(gp),  \
                                   (__attribute__((address_space(3))) void*)(lp), 16, 0, 0)

__device__ __forceinline__ unsigned short f2bf(float f) {
  union { __bf16 h; unsigned short u; } v;
  v.h = (__bf16)f;
  return v.u;
}

__device__ __forceinline__ float sigf(float x) { return 1.f / (1.f + __expf(-x)); }
__device__ __forceinline__ float tanh_fast(float x) {
  float e = __expf(2.f * x);          // x->+inf: e=inf -> 1; x->-inf: e=0 -> -1 (NaN-free)
  return 1.f - 2.f / (e + 1.f);
}

// Convert x [B,T,D] fp32 -> bf16 into workspace; zero the group barrier counters.
__global__ void prep_kernel(const float* __restrict__ x, __bf16* __restrict__ xg,
                            unsigned* __restrict__ cnt) {
  if (blockIdx.x == 0 && threadIdx.x < 16) cnt[threadIdx.x * 32] = 0u;
  size_t i = (size_t)blockIdx.x * blockDim.x + threadIdx.x;
  const size_t n4 = (size_t)BB * TT * DD / 4;
  const size_t stride = (size_t)gridDim.x * blockDim.x;
  const float4* x4 = (const float4*)x;
  uint2* o = (uint2*)xg;
  for (size_t k = i; k < n4; k += stride) {
    float4 v = x4[k];
    uint2 r;
    r.x = (unsigned)f2bf(v.x) | ((unsigned)f2bf(v.y) << 16);
    r.y = (unsigned)f2bf(v.z) | ((unsigned)f2bf(v.w) << 16);
    o[k] = r;
  }
}

// Persistent LSTM scan kernel.
// Grid: 256 WGs x 256 threads. WG (g,s): g = M-group (16 batch rows), s = u-slice (32 gate dims).
// Wave w (4/WG) owns gate w (f,i,c,o), N=32 cols; B-fragments (W 256xK + Ur 512xK slices, bf16)
// live permanently in 192 VGPRs/lane. Cell state c lives in updater-thread registers.
// Per-step sync: per-group monotonic counter in device memory (release add / acquire spin).
__global__ __launch_bounds__(256, 1) void lstm_kernel(
    const __bf16* __restrict__ xg,
    const float* __restrict__ W_f, const float* __restrict__ U_fm,
    const float* __restrict__ P_f, const float* __restrict__ b_f,
    const float* __restrict__ W_i, const float* __restrict__ U_im,
    const float* __restrict__ P_i, const float* __restrict__ b_i,
    const float* __restrict__ W_c, const float* __restrict__ U_cm,
    const float* __restrict__ b_c,
    const float* __restrict__ W_o, const float* __restrict__ U_om,
    const float* __restrict__ P_o, const float* __restrict__ b_o,
    __bf16* __restrict__ hg, unsigned* __restrict__ cnt,
    float* __restrict__ out) {
  __shared__ __align__(16) __bf16 xs[2][16][DD];   // 16 KB: x_t tile, double-buffered
  __shared__ __align__(16) __bf16 hsh[16][UU];     // 16 KB: h_{t-1} tile
  __shared__ float zs[4][16][34];                  // 8.7 KB: z exchange (pad 34 vs bank conflicts)

  const int tid  = threadIdx.x;
  const int lane = tid & 63;
  const int wid  = tid >> 6;
  const int wg = blockIdx.x;
  const int g  = wg >> 4;
  const int s  = wg & 15;
  const int m0 = g * 16;
  const int u0 = s * 32;

  unsigned* cg = cnt + g * 32;

  // ---- stage x(t=0) into xs[0] (overlaps prologue) ----
#pragma unroll
  for (int p = 0; p < 2; ++p) {
    int rbase = wid * 4 + p * 2;
    int r = rbase + (lane >> 5);
    int c = lane & 31;
    int qg = c ^ (r & 7);  // XOR swizzle: stored[c] = logical[c ^ (r&7)]
    const __bf16* gp = xg + ((size_t)(m0 + r) * TT + 0) * DD + qg * 8;
    GLOAD_LDS16(gp, &xs[0][rbase][0]);
  }

  // ---- prologue: load resident B fragments (bf16) ----
  const float* gW = (wid == 0) ? W_f : (wid == 1) ? W_i : (wid == 2) ? W_c : W_o;
  const float* gU = (wid == 0) ? U_fm : (wid == 1) ? U_im : (wid == 2) ? U_cm : U_om;
  const int quad = lane >> 4;
  const int nb = u0 + (lane & 15);

  bf16x8 Bf[24][2];  // kt 0..7: W (K=256), kt 8..23: Ur (K=512); nt: two 16-col tiles
#pragma unroll
  for (int kt = 0; kt < 24; ++kt) {
    const float* src = (kt < 8) ? gW : gU;
    int k0 = (kt < 8) ? kt * 32 + quad * 8 : (kt - 8) * 32 + quad * 8;
#pragma unroll
    for (int nt = 0; nt < 2; ++nt) {
      bf16x8 f;
#pragma unroll
      for (int j = 0; j < 8; ++j) f[j] = (__bf16)src[(k0 + j) * UU + nb + nt * 16];
      Bf[kt][nt] = f;
    }
  }

  // ---- updater-thread setup: (m, u2..u2+1) ownership; c state in registers ----
  const int mloc = tid >> 4;
  const int u2 = (tid & 15) * 2;
  const int ug = u0 + u2;
  float pf0 = P_f[ug], pf1 = P_f[ug + 1];
  float pi0 = P_i[ug], pi1 = P_i[ug + 1];
  float po0 = P_o[ug], po1 = P_o[ug + 1];
  float bf0 = b_f[ug], bf1 = b_f[ug + 1];
  float bi0 = b_i[ug], bi1 = b_i[ug + 1];
  float bc0 = b_c[ug], bc1 = b_c[ug + 1];
  float bo0 = b_o[ug], bo1 = b_o[ug + 1];
  float c0 = 0.f, c1 = 0.f;

  const int rA  = lane & 15;
  const int swz = rA & 7;

  asm volatile("s_waitcnt vmcnt(0)" ::: "memory");
  __syncthreads();

  for (int t = 0; t < TT; ++t) {
    const int xb = t & 1;
    f32x4 acc0 = {0.f, 0.f, 0.f, 0.f};
    f32x4 acc1 = {0.f, 0.f, 0.f, 0.f};

    // A) x-part MFMAs (no h dependency — runs before/while waiting on the barrier)
#pragma unroll
    for (int kt = 0; kt < 8; ++kt) {
      bf16x8 a = *(const bf16x8*)&xs[xb][rA][((kt * 4 + quad) ^ swz) * 8];
      acc0 = __builtin_amdgcn_mfma_f32_16x16x32_bf16(a, Bf[kt][0], acc0, 0, 0, 0);
      acc1 = __builtin_amdgcn_mfma_f32_16x16x32_bf16(a, Bf[kt][1], acc1, 0, 0, 0);
    }

    // B) prefetch x(t+1) into the other LDS buffer
    if (t + 1 < TT) {
#pragma unroll
      for (int p = 0; p < 2; ++p) {
        int rbase = wid * 4 + p * 2;
        int r = rbase + (lane >> 5);
        int c = lane & 31;
        int qg = c ^ (r & 7);
        const __bf16* gp = xg + ((size_t)(m0 + r) * TT + (t + 1)) * DD + qg * 8;
        GLOAD_LDS16(gp, &xs[xb ^ 1][rbase][0]);
      }
    }

    // C/D) wait for all 16 WGs of this M-group to publish h_t, then stage it
    if (t > 0) {
      if (tid == 0) {
        unsigned tgt = 16u * (unsigned)t;
        while (__hip_atomic_load(cg, __ATOMIC_ACQUIRE, __HIP_MEMORY_SCOPE_AGENT) < tgt)
          __builtin_amdgcn_s_sleep(1);
      }
      __syncthreads();
      const __bf16* hb = hg + (size_t)(t & 1) * (BB * UU);
#pragma unroll
      for (int p = 0; p < 4; ++p) {
        int r = wid * 4 + p;
        int qg = lane ^ (r & 7);
        const __bf16* gp = hb + (size_t)(m0 + r) * UU + qg * 8;
        GLOAD_LDS16(gp, &hsh[r][0]);
      }
    }
    asm volatile("s_waitcnt vmcnt(0)" ::: "memory");
    __syncthreads();

    // E) h-part MFMAs
    if (t > 0) {
#pragma unroll
      for (int kt = 0; kt < 16; ++kt) {
        bf16x8 a = *(const bf16x8*)&hsh[rA][((kt * 4 + quad) ^ swz) * 8];
        acc0 = __builtin_amdgcn_mfma_f32_16x16x32_bf16(a, Bf[8 + kt][0], acc0, 0, 0, 0);
        acc1 = __builtin_amdgcn_mfma_f32_16x16x32_bf16(a, Bf[8 + kt][1], acc1, 0, 0, 0);
      }
    }

    // F) z exchange: C/D layout col=lane&15, row=quad*4+reg
#pragma unroll
    for (int r = 0; r < 4; ++r) {
      zs[wid][quad * 4 + r][lane & 15] = acc0[r];
      zs[wid][quad * 4 + r][16 + (lane & 15)] = acc1[r];
    }
    __syncthreads();

    // G) gate math + state update + h/out writes
    {
      float2 vzf = *(const float2*)&zs[0][mloc][u2];
      float2 vzi = *(const float2*)&zs[1][mloc][u2];
      float2 vzc = *(const float2*)&zs[2][mloc][u2];
      float2 vzo = *(const float2*)&zs[3][mloc][u2];

      float f0 = sigf(vzf.x + c0 * pf0 + bf0);
      float f1 = sigf(vzf.y + c1 * pf1 + bf1);
      float i0 = sigf(vzi.x + c0 * pi0 + bi0);
      float i1 = sigf(vzi.y + c1 * pi1 + bi1);
      float cc0 = tanh_fast(vzc.x + bc0);
      float cc1 = tanh_fast(vzc.y + bc1);
      c0 = f0 * c0 + i0 * cc0;
      c1 = f1 * c1 + i1 * cc1;
      float o0 = sigf(vzo.x + c0 * po0 + bo0);
      float o1 = sigf(vzo.y + c1 * po1 + bo1);
      float h0 = o0 * tanh_fast(c0);
      float h1 = o1 * tanh_fast(c1);

      __bf16* hn = hg + (size_t)((t + 1) & 1) * (BB * UU);
      unsigned hp = (unsigned)f2bf(h0) | ((unsigned)f2bf(h1) << 16);
      *(unsigned*)&hn[(size_t)(m0 + mloc) * UU + ug] = hp;

      float2 ov;
      ov.x = h0;
      ov.y = h1;
      *(float2*)&out[((size_t)(m0 + mloc) * TT + t) * UU + ug] = ov;
    }
    __syncthreads();

    // H) publish h_{t+1}: release-add to the group counter
    if (tid == 0)
      __hip_atomic_fetch_add(cg, 1u, __ATOMIC_RELEASE, __HIP_MEMORY_SCOPE_AGENT);
  }
}

extern "C" void kernel_launch(void* const* d_in, const int* in_sizes, int n_in,
                              void* d_out, int out_size, void* d_ws, size_t ws_size,
                              hipStream_t stream) {
  const float* x   = (const float*)d_in[0];
  const float* W_f = (const float*)d_in[1];
  const float* U_f = (const float*)d_in[2];
  const float* P_f = (const float*)d_in[3];
  const float* b_f = (const float*)d_in[4];
  const float* W_i = (const float*)d_in[5];
  const float* U_i = (const float*)d_in[6];
  const float* P_i = (const float*)d_in[7];
  const float* b_i = (const float*)d_in[8];
  const float* W_c = (const float*)d_in[9];
  const float* U_c = (const float*)d_in[10];
  const float* b_c = (const float*)d_in[11];
  const float* W_o = (const float*)d_in[12];
  const float* U_o = (const float*)d_in[13];
  const float* P_o = (const float*)d_in[14];
  const float* b_o = (const float*)d_in[15];

  const size_t XBYTES = (size_t)BB * TT * DD * 2;   // 64 MiB x in bf16
  const size_t HBYTES = (size_t)2 * BB * UU * 2;    // 512 KiB h double buffer
  __bf16* xg = (__bf16*)d_ws;
  __bf16* hg = (__bf16*)((char*)d_ws + XBYTES);
  unsigned* cnt = (unsigned*)((char*)d_ws + XBYTES + HBYTES);

  prep_kernel<<<2048, 256, 0, stream>>>(x, xg, cnt);
  lstm_kernel<<<256, 256, 0, stream>>>(xg, W_f, U_f, P_f, b_f, W_i, U_i, P_i, b_i,
                                       W_c, U_c, b_c, W_o, U_o, P_o, b_o,
                                       hg, cnt, (float*)d_out);
}

// Round 2
// 2970.113 us; speedup vs baseline: 2.5142x; 2.5142x over previous
//
#include <hip/hip_runtime.h>

#define BB 256
#define TT 512
#define DD 256
#define UU 512

typedef float f32x4 __attribute__((ext_vector_type(4)));
typedef __bf16 bf16x8 __attribute__((ext_vector_type(8)));

#define GLOAD_LDS16(gp, lp)                                                              \
  __builtin_amdgcn_global_load_lds((const __attribute__((address_space(1))) void*)(gp),  \
                                   (__attribute__((address_space(3))) void*)(lp), 16, 0, 0)

#define ALOAD64(p)  __hip_atomic_load((p), __ATOMIC_RELAXED, __HIP_MEMORY_SCOPE_AGENT)
#define ALOAD32(p)  __hip_atomic_load((p), __ATOMIC_RELAXED, __HIP_MEMORY_SCOPE_AGENT)
#define ASTORE32(p, v) __hip_atomic_store((p), (v), __ATOMIC_RELAXED, __HIP_MEMORY_SCOPE_AGENT)

__device__ __forceinline__ unsigned short f2bf(float f) {
  union { __bf16 h; unsigned short u; } v;
  v.h = (__bf16)f;
  return v.u;
}

__device__ __forceinline__ float sigf(float x) { return 1.f / (1.f + __expf(-x)); }
__device__ __forceinline__ float tanh_fast(float x) {
  float e = __expf(2.f * x);          // x->+inf: e=inf -> 1; x->-inf: e=0 -> -1 (NaN-free)
  return 1.f - 2.f / (e + 1.f);
}

// Convert x [B,T,D] fp32 -> bf16 into workspace; zero the group barrier counters.
__global__ void prep_kernel(const float* __restrict__ x, __bf16* __restrict__ xg,
                            unsigned* __restrict__ cnt) {
  if (blockIdx.x == 0 && threadIdx.x < 16) cnt[threadIdx.x * 32] = 0u;
  size_t i = (size_t)blockIdx.x * blockDim.x + threadIdx.x;
  const size_t n4 = (size_t)BB * TT * DD / 4;
  const size_t stride = (size_t)gridDim.x * blockDim.x;
  const float4* x4 = (const float4*)x;
  uint2* o = (uint2*)xg;
  for (size_t k = i; k < n4; k += stride) {
    float4 v = x4[k];
    uint2 r;
    r.x = (unsigned)f2bf(v.x) | ((unsigned)f2bf(v.y) << 16);
    r.y = (unsigned)f2bf(v.z) | ((unsigned)f2bf(v.w) << 16);
    o[k] = r;
  }
}

// Persistent LSTM scan kernel.
// Grid: 256 WGs x 256 threads. WG (g,s): g = M-group (16 batch rows), s = u-slice (32 gate dims).
// Wave w (4/WG) owns gate w (f,i,c,o), N=32 cols; B-fragments live permanently in VGPRs/AGPRs.
// Cross-WG h exchange goes through the LLC via RELAXED agent-scope atomics ONLY (no
// acquire/release -> no buffer_inv / buffer_wbl2 L2 maintenance, which was R1's 14us/step).
// Ordering: producer h-stores are vmcnt-drained by __syncthreads before the counter add;
// consumers poll the counter, then read h straight into MFMA A-fragments (no LDS staging).
__global__ __launch_bounds__(256, 1) void lstm_kernel(
    const __bf16* __restrict__ xg,
    const float* __restrict__ W_f, const float* __restrict__ U_fm,
    const float* __restrict__ P_f, const float* __restrict__ b_f,
    const float* __restrict__ W_i, const float* __restrict__ U_im,
    const float* __restrict__ P_i, const float* __restrict__ b_i,
    const float* __restrict__ W_c, const float* __restrict__ U_cm,
    const float* __restrict__ b_c,
    const float* __restrict__ W_o, const float* __restrict__ U_om,
    const float* __restrict__ P_o, const float* __restrict__ b_o,
    __bf16* __restrict__ hg, unsigned* __restrict__ cnt,
    float* __restrict__ out) {
  __shared__ __align__(16) __bf16 xs[2][16][DD];   // 16 KB: x_t tile, double-buffered
  __shared__ float zs[4][16][34];                  // 8.7 KB: z exchange (pad 34 vs bank conflicts)

  const int tid  = threadIdx.x;
  const int lane = tid & 63;
  const int wid  = tid >> 6;
  const int wg = blockIdx.x;
  const int g  = wg >> 4;
  const int s  = wg & 15;
  const int m0 = g * 16;
  const int u0 = s * 32;

  unsigned* cg = cnt + g * 32;

  // ---- stage x(t=0) into xs[0] (overlaps prologue) ----
#pragma unroll
  for (int p = 0; p < 2; ++p) {
    int rbase = wid * 4 + p * 2;
    int r = rbase + (lane >> 5);
    int c = lane & 31;
    int qg = c ^ (r & 7);  // XOR swizzle: stored[c] = logical[c ^ (r&7)]
    const __bf16* gp = xg + ((size_t)(m0 + r) * TT + 0) * DD + qg * 8;
    GLOAD_LDS16(gp, &xs[0][rbase][0]);
  }

  // ---- prologue: load resident B fragments (bf16) ----
  const float* gW = (wid == 0) ? W_f : (wid == 1) ? W_i : (wid == 2) ? W_c : W_o;
  const float* gU = (wid == 0) ? U_fm : (wid == 1) ? U_im : (wid == 2) ? U_cm : U_om;
  const int quad = lane >> 4;
  const int nb = u0 + (lane & 15);

  bf16x8 Bf[24][2];  // kt 0..7: W (K=256), kt 8..23: Ur (K=512); nt: two 16-col tiles
#pragma unroll
  for (int kt = 0; kt < 24; ++kt) {
    const float* src = (kt < 8) ? gW : gU;
    int k0 = (kt < 8) ? kt * 32 + quad * 8 : (kt - 8) * 32 + quad * 8;
#pragma unroll
    for (int nt = 0; nt < 2; ++nt) {
      bf16x8 f;
#pragma unroll
      for (int j = 0; j < 8; ++j) f[j] = (__bf16)src[(k0 + j) * UU + nb + nt * 16];
      Bf[kt][nt] = f;
    }
  }

  // ---- updater-thread setup: (m, u2..u2+1) ownership; c state in registers ----
  const int mloc = tid >> 4;
  const int u2 = (tid & 15) * 2;
  const int ug = u0 + u2;
  float pf0 = P_f[ug], pf1 = P_f[ug + 1];
  float pi0 = P_i[ug], pi1 = P_i[ug + 1];
  float po0 = P_o[ug], po1 = P_o[ug + 1];
  float bf0 = b_f[ug], bf1 = b_f[ug + 1];
  float bi0 = b_i[ug], bi1 = b_i[ug + 1];
  float bc0 = b_c[ug], bc1 = b_c[ug + 1];
  float bo0 = b_o[ug], bo1 = b_o[ug + 1];
  float c0 = 0.f, c1 = 0.f;

  const int rA  = lane & 15;
  const int swz = rA & 7;

  asm volatile("s_waitcnt vmcnt(0)" ::: "memory");
  __syncthreads();

  for (int t = 0; t < TT; ++t) {
    const int xb = t & 1;
    f32x4 acc0 = {0.f, 0.f, 0.f, 0.f};
    f32x4 acc1 = {0.f, 0.f, 0.f, 0.f};

    // A) x-part MFMAs (no h dependency — overlaps the barrier wait below)
#pragma unroll
    for (int kt = 0; kt < 8; ++kt) {
      bf16x8 a = *(const bf16x8*)&xs[xb][rA][((kt * 4 + quad) ^ swz) * 8];
      acc0 = __builtin_amdgcn_mfma_f32_16x16x32_bf16(a, Bf[kt][0], acc0, 0, 0, 0);
      acc1 = __builtin_amdgcn_mfma_f32_16x16x32_bf16(a, Bf[kt][1], acc1, 0, 0, 0);
    }

    // B) prefetch x(t+1) into the other LDS buffer (plain cached path — not communicated)
    if (t + 1 < TT) {
#pragma unroll
      for (int p = 0; p < 2; ++p) {
        int rbase = wid * 4 + p * 2;
        int r = rbase + (lane >> 5);
        int c = lane & 31;
        int qg = c ^ (r & 7);
        const __bf16* gp = xg + ((size_t)(m0 + r) * TT + (t + 1)) * DD + qg * 8;
        GLOAD_LDS16(gp, &xs[xb ^ 1][rbase][0]);
      }
    }

    // C) wait for all 16 WGs of this M-group to have published h_t (relaxed polls only)
    if (t > 0) {
      if (tid == 0) {
        const unsigned tgt = 16u * (unsigned)t;
        while (ALOAD32(cg) < tgt) __builtin_amdgcn_s_sleep(1);
      }
      __syncthreads();

      // D/E) read h_t straight from LLC into A-fragments, interleaved with h-MFMAs
      const __bf16* hb = hg + (size_t)(t & 1) * (BB * UU);
      const unsigned long long* hrow =
          (const unsigned long long*)(hb + (size_t)(m0 + rA) * UU);
      unsigned long long hv[8], hw[8];
#pragma unroll
      for (int jj = 0; jj < 4; ++jj) {   // group 0: kt 0..3
        int base = jj * 8 + quad * 2;
        hv[jj * 2]     = ALOAD64(hrow + base);
        hv[jj * 2 + 1] = ALOAD64(hrow + base + 1);
      }
#pragma unroll
      for (int gi = 0; gi < 4; ++gi) {
        unsigned long long* cur = (gi & 1) ? hw : hv;
        unsigned long long* nxt = (gi & 1) ? hv : hw;
        if (gi < 3) {
#pragma unroll
          for (int jj = 0; jj < 4; ++jj) {  // prefetch group gi+1
            int kt = (gi + 1) * 4 + jj;
            int base = kt * 8 + quad * 2;
            nxt[jj * 2]     = ALOAD64(hrow + base);
            nxt[jj * 2 + 1] = ALOAD64(hrow + base + 1);
          }
        }
#pragma unroll
        for (int jj = 0; jj < 4; ++jj) {
          int kt = gi * 4 + jj;
          union { unsigned long long u[2]; bf16x8 v; } a;
          a.u[0] = cur[jj * 2];
          a.u[1] = cur[jj * 2 + 1];
          acc0 = __builtin_amdgcn_mfma_f32_16x16x32_bf16(a.v, Bf[8 + kt][0], acc0, 0, 0, 0);
          acc1 = __builtin_amdgcn_mfma_f32_16x16x32_bf16(a.v, Bf[8 + kt][1], acc1, 0, 0, 0);
        }
      }
    }

    // F) z exchange: C/D layout col=lane&15, row=quad*4+reg
#pragma unroll
    for (int r = 0; r < 4; ++r) {
      zs[wid][quad * 4 + r][lane & 15] = acc0[r];
      zs[wid][quad * 4 + r][16 + (lane & 15)] = acc1[r];
    }
    __syncthreads();

    // G) gate math + state update + h/out writes
    {
      float2 vzf = *(const float2*)&zs[0][mloc][u2];
      float2 vzi = *(const float2*)&zs[1][mloc][u2];
      float2 vzc = *(const float2*)&zs[2][mloc][u2];
      float2 vzo = *(const float2*)&zs[3][mloc][u2];

      float f0 = sigf(vzf.x + c0 * pf0 + bf0);
      float f1 = sigf(vzf.y + c1 * pf1 + bf1);
      float i0 = sigf(vzi.x + c0 * pi0 + bi0);
      float i1 = sigf(vzi.y + c1 * pi1 + bi1);
      float cc0 = tanh_fast(vzc.x + bc0);
      float cc1 = tanh_fast(vzc.y + bc1);
      c0 = f0 * c0 + i0 * cc0;
      c1 = f1 * c1 + i1 * cc1;
      float o0 = sigf(vzo.x + c0 * po0 + bo0);
      float o1 = sigf(vzo.y + c1 * po1 + bo1);
      float h0 = o0 * tanh_fast(c0);
      float h1 = o1 * tanh_fast(c1);

      // publish h through the LLC (relaxed agent store -> sc-flagged write, no L2 residue)
      __bf16* hn = hg + (size_t)((t + 1) & 1) * (BB * UU);
      unsigned hp = (unsigned)f2bf(h0) | ((unsigned)f2bf(h1) << 16);
      ASTORE32((unsigned*)&hn[(size_t)(m0 + mloc) * UU + ug], hp);

      float2 ov;
      ov.x = h0;
      ov.y = h1;
      *(float2*)&out[((size_t)(m0 + mloc) * TT + t) * UU + ug] = ov;
    }

    // H) drain all h stores (barrier implies vmcnt(0)), then one release-free counter add
    __syncthreads();
    if (tid == 0)
      __hip_atomic_fetch_add(cg, 1u, __ATOMIC_RELAXED, __HIP_MEMORY_SCOPE_AGENT);
  }
}

extern "C" void kernel_launch(void* const* d_in, const int* in_sizes, int n_in,
                              void* d_out, int out_size, void* d_ws, size_t ws_size,
                              hipStream_t stream) {
  const float* x   = (const float*)d_in[0];
  const float* W_f = (const float*)d_in[1];
  const float* U_f = (const float*)d_in[2];
  const float* P_f = (const float*)d_in[3];
  const float* b_f = (const float*)d_in[4];
  const float* W_i = (const float*)d_in[5];
  const float* U_i = (const float*)d_in[6];
  const float* P_i = (const float*)d_in[7];
  const float* b_i = (const float*)d_in[8];
  const float* W_c = (const float*)d_in[9];
  const float* U_c = (const float*)d_in[10];
  const float* b_c = (const float*)d_in[11];
  const float* W_o = (const float*)d_in[12];
  const float* U_o = (const float*)d_in[13];
  const float* P_o = (const float*)d_in[14];
  const float* b_o = (const float*)d_in[15];

  const size_t XBYTES = (size_t)BB * TT * DD * 2;   // 64 MiB x in bf16
  const size_t HBYTES = (size_t)2 * BB * UU * 2;    // 512 KiB h double buffer
  __bf16* xg = (__bf16*)d_ws;
  __bf16* hg = (__bf16*)((char*)d_ws + XBYTES);
  unsigned* cnt = (unsigned*)((char*)d_ws + XBYTES + HBYTES);

  prep_kernel<<<2048, 256, 0, stream>>>(x, xg, cnt);
  lstm_kernel<<<256, 256, 0, stream>>>(xg, W_f, U_f, P_f, b_f, W_i, U_i, P_i, b_i,
                                       W_c, U_c, b_c, W_o, U_o, P_o, b_o,
                                       hg, cnt, (float*)d_out);
}